// Round 1
// baseline (513.137 us; speedup 1.0000x reference)
//
#include <hip/hip_runtime.h>
#include <hip/hip_bf16.h>
#include <math.h>

#define Bb 8
#define Nn 400
#define GN 2
#define INF 66        // INPUT_DIM + HIDDEN
#define IDIM 330      // (GN*HOP_K+1)*INF
#define HID 64
#define EMB 16
constexpr int M = Bb * Nn;   // 3200 nodes

// ---------------- stage 0: concat x,state into H[:,0:66] ----------------
__global__ void k_concat(const float* __restrict__ x, const float* __restrict__ state,
                         float* __restrict__ Hb) {
    int idx = blockIdx.x * blockDim.x + threadIdx.x;
    if (idx >= M * INF) return;
    int node = idx / INF, c = idx % INF;
    float v = (c < 2) ? x[node * 2 + c] : state[node * HID + (c - 2)];
    Hb[(size_t)node * IDIM + c] = v;
}

// ---------------- stage 1: graph hop (bnm,bmd->bnd) ----------------
// grid (25, B, GN), block 256. Row tile = 16.
__global__ void k_hop(const float* __restrict__ G, float* __restrict__ Hb, int hop) {
    const int b = blockIdx.y, g = blockIdx.z;
    const int row0 = blockIdx.x * 16;
    const int in_off = (hop == 0) ? 0 : (66 + g * 132);
    const int out_off = 66 + g * 132 + hop * 66;

    __shared__ float Xs[100][INF + 1];   // 100x67 floats = 26.8 KB

    float acc[5];
#pragma unroll
    for (int j = 0; j < 5; j++) acc[j] = 0.f;

    const float* Gb = G + (size_t)(g * Bb + b) * Nn * Nn;
    const float* Hin = Hb + (size_t)b * Nn * IDIM + in_off;

    for (int m0 = 0; m0 < Nn; m0 += 100) {
        for (int t = threadIdx.x; t < 100 * INF; t += 256) {
            int mm = t / INF, c = t % INF;
            Xs[mm][c] = Hin[(size_t)(m0 + mm) * IDIM + c];
        }
        __syncthreads();
#pragma unroll
        for (int j = 0; j < 5; j++) {
            int idx = threadIdx.x + j * 256;
            if (idx < 16 * INF) {
                int rr = idx / INF, c = idx % INF;
                int row = row0 + rr;
                const float* Grow = Gb + (size_t)row * Nn + m0;
                float a = acc[j];
#pragma unroll 4
                for (int mm = 0; mm < 100; mm++) a += Grow[mm] * Xs[mm][c];
                acc[j] = a;
            }
        }
        __syncthreads();
    }

    float* Hout = Hb + (size_t)b * Nn * IDIM + out_off;
#pragma unroll
    for (int j = 0; j < 5; j++) {
        int idx = threadIdx.x + j * 256;
        if (idx < 16 * INF) {
            int rr = idx / INF, c = idx % INF;
            Hout[(size_t)(row0 + rr) * IDIM + c] = acc[j];
        }
    }
}

// ---------------- stage 2: meta GEMM  Q[m, d*O+o] = sum_i H[m,i] * W[d,i,o] ----------------
// [3200,330] x [330, 16*O].  BM=BN=64, BK=16, 256 threads, 4x4 micro-tile.
template <int O>
__global__ void k_meta_gemm(const float* __restrict__ Hb, const float* __restrict__ W,
                            float* __restrict__ Q) {
    constexpr int NC = EMB * O;
    __shared__ float As[16][64 + 1];
    __shared__ float Bs[16][64 + 1];
    const int bm = blockIdx.y * 64, bn = blockIdx.x * 64;
    const int tx = threadIdx.x % 16, ty = threadIdx.x / 16;
    float acc[4][4] = {};

    for (int k0 = 0; k0 < IDIM; k0 += 16) {
        for (int t = threadIdx.x; t < 64 * 16; t += 256) {
            int r = t / 16, kk = t % 16;
            int k = k0 + kk;
            As[kk][r] = (k < IDIM) ? Hb[(size_t)(bm + r) * IDIM + k] : 0.f;
        }
        for (int t = threadIdx.x; t < 16 * 64; t += 256) {
            int kk = t / 64, c = t % 64;
            int k = k0 + kk, col = bn + c;
            int d = col / O, o = col % O;
            Bs[kk][c] = (k < IDIM) ? W[((size_t)d * IDIM + k) * O + o] : 0.f;
        }
        __syncthreads();
#pragma unroll
        for (int kk = 0; kk < 16; kk++) {
            float av[4], bv[4];
#pragma unroll
            for (int i = 0; i < 4; i++) av[i] = As[kk][ty * 4 + i];
#pragma unroll
            for (int j = 0; j < 4; j++) bv[j] = Bs[kk][tx * 4 + j];
#pragma unroll
            for (int i = 0; i < 4; i++)
#pragma unroll
                for (int j = 0; j < 4; j++) acc[i][j] += av[i] * bv[j];
        }
        __syncthreads();
    }
#pragma unroll
    for (int i = 0; i < 4; i++)
#pragma unroll
        for (int j = 0; j < 4; j++)
            Q[(size_t)(bm + ty * 4 + i) * NC + bn + tx * 4 + j] = acc[i][j];
}

// ---------------- stage 3: z/r reduction + gate; writes z and H2's p0 ----------------
__global__ void k_reduce_zr(const float* __restrict__ Q, const float* __restrict__ emb,
                            const float* __restrict__ bg, const float* __restrict__ x,
                            const float* __restrict__ state, float* __restrict__ zbuf,
                            float* __restrict__ H2) {
    int node = blockIdx.x;
    int o = threadIdx.x;   // 0..127
    __shared__ float es[EMB];
    if (threadIdx.x < EMB) es[threadIdx.x] = emb[node * EMB + threadIdx.x];
    __syncthreads();
    const float* Qrow = Q + (size_t)node * (EMB * 128);
    float val = 0.f;
#pragma unroll
    for (int d = 0; d < EMB; d++) val += es[d] * (Qrow[d * 128 + o] + bg[d * 128 + o]);
    float s = 1.f / (1.f + expf(-val));
    if (o < 64) {
        zbuf[node * 64 + o] = s;
    } else {
        int oo = o - 64;
        H2[(size_t)node * IDIM + 2 + oo] = s * state[node * 64 + oo];
    }
    if (o < 2) H2[(size_t)node * IDIM + o] = x[node * 2 + o];
}

// ---------------- stage 4: hc reduction + GRU blend ----------------
__global__ void k_final(const float* __restrict__ Q, const float* __restrict__ emb,
                        const float* __restrict__ bc, const float* __restrict__ zbuf,
                        const float* __restrict__ state, float* __restrict__ out) {
    int node = blockIdx.x;
    int o = threadIdx.x;   // 0..63
    __shared__ float es[EMB];
    if (threadIdx.x < EMB) es[threadIdx.x] = emb[node * EMB + threadIdx.x];
    __syncthreads();
    const float* Qrow = Q + (size_t)node * (EMB * 64);
    float val = 0.f;
#pragma unroll
    for (int d = 0; d < EMB; d++) val += es[d] * (Qrow[d * 64 + o] + bc[d * 64 + o]);
    float hc = tanhf(val);
    float z = zbuf[node * 64 + o];
    out[node * 64 + o] = z * state[node * 64 + o] + (1.f - z) * hc;
}

extern "C" void kernel_launch(void* const* d_in, const int* in_sizes, int n_in,
                              void* d_out, int out_size, void* d_ws, size_t ws_size,
                              hipStream_t stream) {
    const float* x      = (const float*)d_in[0];
    const float* state  = (const float*)d_in[1];
    const float* graphs = (const float*)d_in[2];
    const float* emb    = (const float*)d_in[3];
    const float* Wg     = (const float*)d_in[4];
    const float* bg     = (const float*)d_in[5];
    const float* Wc     = (const float*)d_in[6];
    const float* bc     = (const float*)d_in[7];
    float* out = (float*)d_out;

    float* Hb = (float*)d_ws;                       // M*330 floats
    float* Qb = Hb + (size_t)M * IDIM;              // M*2048 floats
    float* zb = Qb + (size_t)M * (EMB * 128);       // M*64 floats

    dim3 hopgrid(25, Bb, GN);

    // ---- first meta_dgcn (gates) ----
    k_concat<<<(M * INF + 255) / 256, 256, 0, stream>>>(x, state, Hb);
    k_hop<<<hopgrid, 256, 0, stream>>>(graphs, Hb, 0);
    k_hop<<<hopgrid, 256, 0, stream>>>(graphs, Hb, 1);
    k_meta_gemm<128><<<dim3(32, 50), 256, 0, stream>>>(Hb, Wg, Qb);
    k_reduce_zr<<<M, 128, 0, stream>>>(Qb, emb, bg, x, state, zb, Hb);

    // ---- second meta_dgcn (candidate), H2 aliases H1 ----
    k_hop<<<hopgrid, 256, 0, stream>>>(graphs, Hb, 0);
    k_hop<<<hopgrid, 256, 0, stream>>>(graphs, Hb, 1);
    k_meta_gemm<64><<<dim3(16, 50), 256, 0, stream>>>(Hb, Wc, Qb);
    k_final<<<M, 64, 0, stream>>>(Qb, emb, bc, zb, state, out);
}

// Round 2
// 246.636 us; speedup vs baseline: 2.0805x; 2.0805x over previous
//
#include <hip/hip_runtime.h>
#include <hip/hip_bf16.h>
#include <math.h>

#define Bb 8
#define Nn 400
#define GN 2
#define INF 66        // INPUT_DIM + HIDDEN
#define IDIM 330      // logical K
#define KP 352        // K padded to 32
#define HID 64
#define EMB 16
constexpr int M = Bb * Nn;   // 3200 nodes

typedef __attribute__((ext_vector_type(8))) short short8;   // 8 x bf16 frag
typedef __attribute__((ext_vector_type(4))) float f32x4;

__device__ __forceinline__ ushort f2bf(float f) {
    union { float f; unsigned u; } v; v.f = f;
    unsigned u = v.u;
    unsigned r = (u + 0x7FFFu + ((u >> 16) & 1u)) >> 16;
    return (ushort)r;
}

// ---------- convert graphs -> bf16, K padded 400->416 ----------
__global__ void k_gconv(const float* __restrict__ G, ushort* __restrict__ Gbf) {
    size_t idx = (size_t)blockIdx.x * 256 + threadIdx.x;
    constexpr size_t TOT = (size_t)GN * Bb * Nn * 416;
    if (idx >= TOT) return;
    int k = (int)(idx % 416);
    size_t row = idx / 416;
    Gbf[idx] = (k < Nn) ? f2bf(G[row * Nn + k]) : (ushort)0;
}

// ---------- convert W[d,i,o] -> WT[c=d*O+o][k] bf16, k padded to 352 ----------
// grid (11, NC/64), block 256
__global__ void k_wT(const float* __restrict__ W, ushort* __restrict__ WT, int O) {
    __shared__ float T[32][65];
    const int k0 = blockIdx.x * 32;
    const int c0 = blockIdx.y * 64;
    const int d = c0 / O, o0 = c0 % O;
    for (int e = threadIdx.x; e < 2048; e += 256) {
        int kk = e >> 6, oo = e & 63;
        int k = k0 + kk;
        T[kk][oo] = (k < IDIM) ? W[((size_t)d * IDIM + k) * O + o0 + oo] : 0.f;
    }
    __syncthreads();
    for (int e = threadIdx.x; e < 2048; e += 256) {
        int cc = e >> 5, kk = e & 31;
        WT[(size_t)(c0 + cc) * KP + k0 + kk] = f2bf(T[kk][cc]);
    }
}

// ---------- concat x,state -> Hbf cols 0..65, zero cols 330..351 ----------
__global__ void k_concat_bf(const float* __restrict__ x, const float* __restrict__ state,
                            ushort* __restrict__ Hbf) {
    int idx = blockIdx.x * 256 + threadIdx.x;
    if (idx >= M * 88) return;
    int node = idx / 88, c = idx % 88;
    ushort v;
    int col;
    if (c < 2)       { v = f2bf(x[node * 2 + c]); col = c; }
    else if (c < 66) { v = f2bf(state[node * HID + c - 2]); col = c; }
    else             { v = 0; col = 330 + (c - 66); }
    Hbf[(size_t)node * KP + col] = v;
}

// ---------- graph hop via MFMA: C[400x66] = G[400x400] * X[400x66] per (b,g) ----------
// grid (7, B, GN), block 256 (4 waves); wave w handles rows row0+w*16..+15, cols 0..79
__global__ void k_hop(const ushort* __restrict__ Gbf, ushort* __restrict__ Hbf, int hop) {
    const int b = blockIdx.y, g = blockIdx.z;
    const int row0 = blockIdx.x * 64;
    const int in_off  = (hop == 0) ? 0 : (66 + g * 132);
    const int out_off = 66 + g * 132 + hop * 66;
    const int wid = threadIdx.x >> 6, lane = threadIdx.x & 63;
    const int lr = lane & 15, kq = lane >> 4;

    __shared__ ushort XsT[80][40];   // [col][k] padded

    const ushort* Gb  = Gbf + (size_t)(g * Bb + b) * Nn * 416;
    const ushort* Hin = Hbf + (size_t)b * Nn * KP + in_off;

    f32x4 acc[5] = {};
    int arow = row0 + wid * 16 + lr;
    if (arow > Nn - 1) arow = Nn - 1;

    for (int ks = 0; ks < 13; ks++) {
        int k0 = ks * 32;
        __syncthreads();
        for (int e = threadIdx.x; e < 2560; e += 256) {
            int kk = e / 80, c = e % 80;
            int k = k0 + kk;
            XsT[c][kk] = (k < Nn && c < INF) ? Hin[(size_t)k * KP + c] : (ushort)0;
        }
        __syncthreads();
        short8 af = *(const short8*)(Gb + (size_t)arow * 416 + k0 + kq * 8);
#pragma unroll
        for (int n = 0; n < 5; n++) {
            short8 bv = *(const short8*)(&XsT[n * 16 + lr][kq * 8]);
            acc[n] = __builtin_amdgcn_mfma_f32_16x16x32_bf16(af, bv, acc[n], 0, 0, 0);
        }
    }

    ushort* Hout = Hbf + (size_t)b * Nn * KP + out_off;
    int rbase = row0 + wid * 16 + kq * 4;
#pragma unroll
    for (int n = 0; n < 5; n++) {
        int col = n * 16 + lr;
        if (col < INF) {
#pragma unroll
            for (int r = 0; r < 4; r++) {
                int row = rbase + r;
                if (row < Nn) Hout[(size_t)row * KP + col] = f2bf(acc[n][r]);
            }
        }
    }
}

// ---------- meta GEMM: Q[m, c] = sum_k Hbf[m,k] * WT[c,k]; C = [3200 x NC] ----------
// 128x128 tile, 4 waves (2x2), each wave 64x64 = 4x4 frags of 16x16, K=352 in 11 steps
template <int O>
__global__ void k_meta_gemm(const ushort* __restrict__ Hbf, const ushort* __restrict__ WT,
                            float* __restrict__ Q) {
    constexpr int NC = EMB * O;
    __shared__ ushort As[128][40];
    __shared__ ushort Bs[128][40];
    const int bm = blockIdx.y * 128, bn = blockIdx.x * 128;
    const int wid = threadIdx.x >> 6, lane = threadIdx.x & 63;
    const int wm = wid >> 1, wn = wid & 1;
    const int lr = lane & 15, kq = lane >> 4;
    f32x4 acc[4][4] = {};

    for (int k0 = 0; k0 < KP; k0 += 32) {
        __syncthreads();
#pragma unroll
        for (int p = 0; p < 2; p++) {
            int chunk = threadIdx.x + p * 256;  // 0..511
            int row = chunk >> 2, kc = (chunk & 3) * 8;
            *(short8*)&As[row][kc] = *(const short8*)(Hbf + (size_t)(bm + row) * KP + k0 + kc);
            *(short8*)&Bs[row][kc] = *(const short8*)(WT  + (size_t)(bn + row) * KP + k0 + kc);
        }
        __syncthreads();
        short8 a[4], bv[4];
#pragma unroll
        for (int m = 0; m < 4; m++) a[m] = *(const short8*)&As[wm * 64 + m * 16 + lr][kq * 8];
#pragma unroll
        for (int n = 0; n < 4; n++) bv[n] = *(const short8*)&Bs[wn * 64 + n * 16 + lr][kq * 8];
#pragma unroll
        for (int m = 0; m < 4; m++)
#pragma unroll
            for (int n = 0; n < 4; n++)
                acc[m][n] = __builtin_amdgcn_mfma_f32_16x16x32_bf16(a[m], bv[n], acc[m][n], 0, 0, 0);
    }

    const int rb = bm + wm * 64 + kq * 4;
    const int cb = bn + wn * 64 + lr;
#pragma unroll
    for (int m = 0; m < 4; m++)
#pragma unroll
        for (int n = 0; n < 4; n++)
#pragma unroll
            for (int r = 0; r < 4; r++)
                Q[(size_t)(rb + m * 16 + r) * NC + cb + n * 16] = acc[m][n][r];
}

// ---------- z/r reduction + gate; writes z and Hbf p0' (r*state) in bf16 ----------
__global__ void k_reduce_zr(const float* __restrict__ Q, const float* __restrict__ emb,
                            const float* __restrict__ bg, const float* __restrict__ state,
                            float* __restrict__ zbuf, ushort* __restrict__ Hbf) {
    int node = blockIdx.x;
    int o = threadIdx.x;   // 0..127
    __shared__ float es[EMB];
    if (threadIdx.x < EMB) es[threadIdx.x] = emb[node * EMB + threadIdx.x];
    __syncthreads();
    const float* Qrow = Q + (size_t)node * (EMB * 128);
    float val = 0.f;
#pragma unroll
    for (int d = 0; d < EMB; d++) val += es[d] * (Qrow[d * 128 + o] + bg[d * 128 + o]);
    float s = 1.f / (1.f + expf(-val));
    if (o < 64) {
        zbuf[node * 64 + o] = s;
    } else {
        int oo = o - 64;
        Hbf[(size_t)node * KP + 2 + oo] = f2bf(s * state[node * 64 + oo]);
    }
}

// ---------- hc reduction + GRU blend ----------
__global__ void k_final(const float* __restrict__ Q, const float* __restrict__ emb,
                        const float* __restrict__ bc, const float* __restrict__ zbuf,
                        const float* __restrict__ state, float* __restrict__ out) {
    int node = blockIdx.x;
    int o = threadIdx.x;   // 0..63
    __shared__ float es[EMB];
    if (threadIdx.x < EMB) es[threadIdx.x] = emb[node * EMB + threadIdx.x];
    __syncthreads();
    const float* Qrow = Q + (size_t)node * (EMB * 64);
    float val = 0.f;
#pragma unroll
    for (int d = 0; d < EMB; d++) val += es[d] * (Qrow[d * 64 + o] + bc[d * 64 + o]);
    float hc = tanhf(val);
    float z = zbuf[node * 64 + o];
    out[node * 64 + o] = z * state[node * 64 + o] + (1.f - z) * hc;
}

extern "C" void kernel_launch(void* const* d_in, const int* in_sizes, int n_in,
                              void* d_out, int out_size, void* d_ws, size_t ws_size,
                              hipStream_t stream) {
    const float* x      = (const float*)d_in[0];
    const float* state  = (const float*)d_in[1];
    const float* graphs = (const float*)d_in[2];
    const float* emb    = (const float*)d_in[3];
    const float* Wg     = (const float*)d_in[4];
    const float* bg     = (const float*)d_in[5];
    const float* Wc     = (const float*)d_in[6];
    const float* bc     = (const float*)d_in[7];
    float* out = (float*)d_out;

    char* ws = (char*)d_ws;
    ushort* Hbf = (ushort*)ws;                 ws += (size_t)M * KP * 2;            // 2.25 MB
    ushort* Gbf = (ushort*)ws;                 ws += (size_t)GN * Bb * Nn * 416 * 2; // 5.3 MB
    ushort* WgT = (ushort*)ws;                 ws += (size_t)2048 * KP * 2;         // 1.44 MB
    ushort* WcT = (ushort*)ws;                 ws += (size_t)1024 * KP * 2;         // 0.72 MB
    float*  Qb  = (float*)ws;                  ws += (size_t)M * 2048 * 4;          // 26.2 MB
    float*  zb  = (float*)ws;                                                      // 0.82 MB

    constexpr size_t GTOT = (size_t)GN * Bb * Nn * 416;
    dim3 hopgrid(7, Bb, GN);

    // conversions
    k_gconv<<<(int)((GTOT + 255) / 256), 256, 0, stream>>>(graphs, Gbf);
    k_wT<<<dim3(11, 32), 256, 0, stream>>>(Wg, WgT, 128);
    k_wT<<<dim3(11, 16), 256, 0, stream>>>(Wc, WcT, 64);
    k_concat_bf<<<(M * 88 + 255) / 256, 256, 0, stream>>>(x, state, Hbf);

    // ---- first meta_dgcn (gates) ----
    k_hop<<<hopgrid, 256, 0, stream>>>(Gbf, Hbf, 0);
    k_hop<<<hopgrid, 256, 0, stream>>>(Gbf, Hbf, 1);
    k_meta_gemm<128><<<dim3(16, 25), 256, 0, stream>>>(Hbf, WgT, Qb);
    k_reduce_zr<<<M, 128, 0, stream>>>(Qb, emb, bg, state, zb, Hbf);

    // ---- second meta_dgcn (candidate) ----
    k_hop<<<hopgrid, 256, 0, stream>>>(Gbf, Hbf, 0);
    k_hop<<<hopgrid, 256, 0, stream>>>(Gbf, Hbf, 1);
    k_meta_gemm<64><<<dim3(8, 25), 256, 0, stream>>>(Hbf, WcT, Qb);
    k_final<<<M, 64, 0, stream>>>(Qb, emb, bc, zb, state, out);
}

// Round 3
// 117.626 us; speedup vs baseline: 4.3624x; 2.0968x over previous
//
#include <hip/hip_runtime.h>
#include <hip/hip_bf16.h>
#include <math.h>

#define Bb 8
#define Nn 400
#define GN 2
#define INF 66        // INPUT_DIM + HIDDEN
#define IDIM 330      // logical K
#define KP 352        // K padded to 32
#define HID 64
#define EMB 16
#define NKP 416       // node-dim padded to 32 (400 -> 416)
#define XTR 80        // XT rows (66 cols padded to 80)
constexpr int M = Bb * Nn;   // 3200 nodes

typedef __attribute__((ext_vector_type(8))) short short8;   // 8 x bf16 frag
typedef __attribute__((ext_vector_type(4))) float f32x4;

__device__ __forceinline__ ushort f2bf(float f) {
    union { float f; unsigned u; } v; v.f = f;
    unsigned u = v.u;
    unsigned r = (u + 0x7FFFu + ((u >> 16) & 1u)) >> 16;
    return (ushort)r;
}

// ---------- convert graphs -> bf16, K padded 400->416 ----------
__global__ void k_gconv(const float* __restrict__ G, ushort* __restrict__ Gbf) {
    size_t idx = (size_t)blockIdx.x * 256 + threadIdx.x;
    constexpr size_t TOT = (size_t)GN * Bb * Nn * NKP;
    if (idx >= TOT) return;
    int k = (int)(idx % NKP);
    size_t row = idx / NKP;
    Gbf[idx] = (k < Nn) ? f2bf(G[row * Nn + k]) : (ushort)0;
}

// ---------- convert W[d,i,o] -> WT[c=d*O+o][k] bf16, k padded to 352 ----------
__global__ void k_wT(const float* __restrict__ W, ushort* __restrict__ WT, int O) {
    __shared__ float T[32][65];
    const int k0 = blockIdx.x * 32;
    const int c0 = blockIdx.y * 64;
    const int d = c0 / O, o0 = c0 % O;
    for (int e = threadIdx.x; e < 2048; e += 256) {
        int kk = e >> 6, oo = e & 63;
        int k = k0 + kk;
        T[kk][oo] = (k < IDIM) ? W[((size_t)d * IDIM + k) * O + o0 + oo] : 0.f;
    }
    __syncthreads();
    for (int e = threadIdx.x; e < 2048; e += 256) {
        int cc = e >> 5, kk = e & 31;
        WT[(size_t)(c0 + cc) * KP + k0 + kk] = f2bf(T[kk][cc]);
    }
}

// ---------- concat x,state -> Hbf cols 0..65 (+zero pad 330..351) AND XT_in[b][c][k] ----------
__global__ void k_concat_bf(const float* __restrict__ x, const float* __restrict__ state,
                            ushort* __restrict__ Hbf, ushort* __restrict__ XTin) {
    const int b = blockIdx.y;
    const int k0 = blockIdx.x * 64;
    __shared__ ushort T[64][XTR + 1];
    for (int e = threadIdx.x; e < 64 * XTR; e += 256) {
        int kk = e / XTR, c = e % XTR;
        int k = k0 + kk;
        ushort bf = 0;
        if (k < Nn && c < INF) {
            float v = (c < 2) ? x[((size_t)b * Nn + k) * 2 + c]
                              : state[((size_t)b * Nn + k) * HID + c - 2];
            bf = f2bf(v);
            Hbf[((size_t)b * Nn + k) * KP + c] = bf;
        }
        T[kk][c] = bf;
    }
    for (int e = threadIdx.x; e < 64 * 22; e += 256) {
        int kk = e / 22, c = 330 + e % 22;
        int k = k0 + kk;
        if (k < Nn) Hbf[((size_t)b * Nn + k) * KP + c] = 0;
    }
    __syncthreads();
    for (int e = threadIdx.x; e < XTR * 64; e += 256) {
        int c = e / 64, kk = e % 64;
        int k = k0 + kk;
        if (k < NKP) XTin[((size_t)b * XTR + c) * NKP + k] = T[kk][c];
    }
}

// ---------- graph hop via MFMA, LDS-free ----------
__global__ void k_hop(const ushort* __restrict__ Gbf, const ushort* __restrict__ XT,
                      ushort* __restrict__ Hbf, ushort* __restrict__ XTnext,
                      int out_base, int xt_per_g) {
    const int b = blockIdx.y, g = blockIdx.z;
    const int row0 = blockIdx.x * 64;
    const int wid = threadIdx.x >> 6, lane = threadIdx.x & 63;
    const int lr = lane & 15, kq = lane >> 4;

    const ushort* Gb = Gbf + (size_t)(g * Bb + b) * Nn * NKP;
    const ushort* Xb = XT + (size_t)((xt_per_g ? g * Bb : 0) + b) * XTR * NKP;

    f32x4 acc[5] = {};
    int arow = row0 + wid * 16 + lr;
    if (arow > Nn - 1) arow = Nn - 1;
    const ushort* Grow = Gb + (size_t)arow * NKP;

#pragma unroll
    for (int ks = 0; ks < 13; ks++) {
        short8 af = *(const short8*)(Grow + ks * 32 + kq * 8);
#pragma unroll
        for (int n = 0; n < 5; n++) {
            short8 bv = *(const short8*)(Xb + (size_t)(n * 16 + lr) * NKP + ks * 32 + kq * 8);
            acc[n] = __builtin_amdgcn_mfma_f32_16x16x32_bf16(af, bv, acc[n], 0, 0, 0);
        }
    }

    const int rbase = row0 + wid * 16 + kq * 4;

    ushort* Hout = Hbf + (size_t)b * Nn * KP + out_base + g * 132;
#pragma unroll
    for (int n = 0; n < 5; n++) {
        int col = n * 16 + lr;
        if (col < INF) {
#pragma unroll
            for (int r = 0; r < 4; r++) {
                int row = rbase + r;
                if (row < Nn) Hout[(size_t)row * KP + col] = f2bf(acc[n][r]);
            }
        }
    }

    if (XTnext) {
        ushort* Xn = XTnext + (size_t)(g * Bb + b) * XTR * NKP;
        if (rbase < NKP) {
#pragma unroll
            for (int n = 0; n < 5; n++) {
                int col = n * 16 + lr;
                ushort4 w;
#pragma unroll
                for (int r = 0; r < 4; r++)
                    w[r] = (col < INF && rbase + r < Nn) ? f2bf(acc[n][r]) : (ushort)0;
                *(ushort4*)(Xn + (size_t)col * NKP + rbase) = w;
            }
        }
    }
}

// ---------- meta GEMM ----------
template <int O>
__global__ void k_meta_gemm(const ushort* __restrict__ Hbf, const ushort* __restrict__ WT,
                            float* __restrict__ Q) {
    constexpr int NC = EMB * O;
    __shared__ ushort As[128][40];
    __shared__ ushort Bs[128][40];
    const int bm = blockIdx.y * 128, bn = blockIdx.x * 128;
    const int wid = threadIdx.x >> 6, lane = threadIdx.x & 63;
    const int wm = wid >> 1, wn = wid & 1;
    const int lr = lane & 15, kq = lane >> 4;
    f32x4 acc[4][4] = {};

    for (int k0 = 0; k0 < KP; k0 += 32) {
        __syncthreads();
#pragma unroll
        for (int p = 0; p < 2; p++) {
            int chunk = threadIdx.x + p * 256;
            int row = chunk >> 2, kc = (chunk & 3) * 8;
            *(short8*)&As[row][kc] = *(const short8*)(Hbf + (size_t)(bm + row) * KP + k0 + kc);
            *(short8*)&Bs[row][kc] = *(const short8*)(WT  + (size_t)(bn + row) * KP + k0 + kc);
        }
        __syncthreads();
        short8 a[4], bv[4];
#pragma unroll
        for (int m = 0; m < 4; m++) a[m] = *(const short8*)&As[wm * 64 + m * 16 + lr][kq * 8];
#pragma unroll
        for (int n = 0; n < 4; n++) bv[n] = *(const short8*)&Bs[wn * 64 + n * 16 + lr][kq * 8];
#pragma unroll
        for (int m = 0; m < 4; m++)
#pragma unroll
            for (int n = 0; n < 4; n++)
                acc[m][n] = __builtin_amdgcn_mfma_f32_16x16x32_bf16(a[m], bv[n], acc[m][n], 0, 0, 0);
    }

    const int rb = bm + wm * 64 + kq * 4;
    const int cb = bn + wn * 64 + lr;
#pragma unroll
    for (int m = 0; m < 4; m++)
#pragma unroll
        for (int n = 0; n < 4; n++)
#pragma unroll
            for (int r = 0; r < 4; r++)
                Q[(size_t)(rb + m * 16 + r) * NC + cb + n * 16] = acc[m][n][r];
}

// ---------- z/r reduction + gate ----------
__global__ void k_reduce_zr(const float* __restrict__ Q, const float* __restrict__ emb,
                            const float* __restrict__ bg, const float* __restrict__ state,
                            float* __restrict__ zbuf, ushort* __restrict__ Hbf,
                            ushort* __restrict__ XTin) {
    int node = blockIdx.x;
    int o = threadIdx.x;
    __shared__ float es[EMB];
    if (threadIdx.x < EMB) es[threadIdx.x] = emb[node * EMB + threadIdx.x];
    __syncthreads();
    const float* Qrow = Q + (size_t)node * (EMB * 128);
    float val = 0.f;
#pragma unroll
    for (int d = 0; d < EMB; d++) val += es[d] * (Qrow[d * 128 + o] + bg[d * 128 + o]);
    float s = 1.f / (1.f + expf(-val));
    if (o < 64) {
        zbuf[node * 64 + o] = s;
    } else {
        int oo = o - 64;
        ushort bf = f2bf(s * state[node * 64 + oo]);
        Hbf[(size_t)node * KP + 2 + oo] = bf;
        int b = node / Nn, k = node % Nn;
        XTin[((size_t)b * XTR + 2 + oo) * NKP + k] = bf;
    }
}

// ---------- hc reduction + GRU blend ----------
__global__ void k_final(const float* __restrict__ Q, const float* __restrict__ emb,
                        const float* __restrict__ bc, const float* __restrict__ zbuf,
                        const float* __restrict__ state, float* __restrict__ out) {
    int node = blockIdx.x;
    int o = threadIdx.x;
    __shared__ float es[EMB];
    if (threadIdx.x < EMB) es[threadIdx.x] = emb[node * EMB + threadIdx.x];
    __syncthreads();
    const float* Qrow = Q + (size_t)node * (EMB * 64);
    float val = 0.f;
#pragma unroll
    for (int d = 0; d < EMB; d++) val += es[d] * (Qrow[d * 64 + o] + bc[d * 64 + o]);
    float hc = tanhf(val);
    float z = zbuf[node * 64 + o];
    out[node * 64 + o] = z * state[node * 64 + o] + (1.f - z) * hc;
}

extern "C" void kernel_launch(void* const* d_in, const int* in_sizes, int n_in,
                              void* d_out, int out_size, void* d_ws, size_t ws_size,
                              hipStream_t stream) {
    const float* x      = (const float*)d_in[0];
    const float* state  = (const float*)d_in[1];
    const float* graphs = (const float*)d_in[2];
    const float* emb    = (const float*)d_in[3];
    const float* Wg     = (const float*)d_in[4];
    const float* bg     = (const float*)d_in[5];
    const float* Wc     = (const float*)d_in[6];
    const float* bc     = (const float*)d_in[7];
    float* out = (float*)d_out;

    char* ws = (char*)d_ws;
    ushort* Hbf  = (ushort*)ws;  ws += (size_t)M * KP * 2;
    ushort* Gbf  = (ushort*)ws;  ws += (size_t)GN * Bb * Nn * NKP * 2;
    ushort* WgT  = (ushort*)ws;  ws += (size_t)2048 * KP * 2;
    ushort* WcT  = (ushort*)ws;  ws += (size_t)1024 * KP * 2;
    ushort* XTin = (ushort*)ws;  ws += (size_t)Bb * XTR * NKP * 2;
    ushort* XTmid= (ushort*)ws;  ws += (size_t)GN * Bb * XTR * NKP * 2;
    float*  Qb   = (float*)ws;   ws += (size_t)M * 2048 * 4;
    float*  zb   = (float*)ws;

    constexpr size_t GTOT = (size_t)GN * Bb * Nn * NKP;
    dim3 hopgrid(7, Bb, GN);

    k_gconv<<<(int)((GTOT + 255) / 256), 256, 0, stream>>>(graphs, Gbf);
    k_wT<<<dim3(11, 32), 256, 0, stream>>>(Wg, WgT, 128);
    k_wT<<<dim3(11, 16), 256, 0, stream>>>(Wc, WcT, 64);
    k_concat_bf<<<dim3(7, Bb), 256, 0, stream>>>(x, state, Hbf, XTin);

    k_hop<<<hopgrid, 256, 0, stream>>>(Gbf, XTin, Hbf, XTmid, 66, 0);
    k_hop<<<hopgrid, 256, 0, stream>>>(Gbf, XTmid, Hbf, nullptr, 132, 1);
    k_meta_gemm<128><<<dim3(16, 25), 256, 0, stream>>>(Hbf, WgT, Qb);
    k_reduce_zr<<<M, 128, 0, stream>>>(Qb, emb, bg, state, zb, Hbf, XTin);

    k_hop<<<hopgrid, 256, 0, stream>>>(Gbf, XTin, Hbf, XTmid, 66, 0);
    k_hop<<<hopgrid, 256, 0, stream>>>(Gbf, XTmid, Hbf, nullptr, 132, 1);
    k_meta_gemm<64><<<dim3(8, 25), 256, 0, stream>>>(Hbf, WcT, Qb);
    k_final<<<M, 64, 0, stream>>>(Qb, emb, bc, zb, state, out);
}